// Round 7
// baseline (76.495 us; speedup 1.0000x reference)
//
#include <hip/hip_runtime.h>

#define FXc 384.996f
#define FYc 384.996f
#define CXc 325.85f
#define CYc 237.646f
#define DEPTH_MARGIN 0.003f
#define IMG_H 480
#define IMG_W 640
#define NPIX (IMG_H * IMG_W)

#define SPT 8                 // samples per thread
#define TPB 256               // threads per block
#define SPB (SPT * TPB)       // samples per block = 2048

// ---------- device helper: T = inv(pose_B) @ pose_A (rows 0..2) ----------
__device__ __forceinline__ void make_T(const float* __restrict__ poseA,
                                       const float* __restrict__ poseB,
                                       float* __restrict__ T /*12*/) {
    float m[16], inv[16];
#pragma unroll
    for (int i = 0; i < 16; ++i) m[i] = poseB[i];

    inv[0]  =  m[5]*m[10]*m[15] - m[5]*m[11]*m[14] - m[9]*m[6]*m[15] + m[9]*m[7]*m[14] + m[13]*m[6]*m[11] - m[13]*m[7]*m[10];
    inv[4]  = -m[4]*m[10]*m[15] + m[4]*m[11]*m[14] + m[8]*m[6]*m[15] - m[8]*m[7]*m[14] - m[12]*m[6]*m[11] + m[12]*m[7]*m[10];
    inv[8]  =  m[4]*m[9]*m[15]  - m[4]*m[11]*m[13] - m[8]*m[5]*m[15] + m[8]*m[7]*m[13] + m[12]*m[5]*m[11] - m[12]*m[7]*m[9];
    inv[12] = -m[4]*m[9]*m[14]  + m[4]*m[10]*m[13] + m[8]*m[5]*m[14] - m[8]*m[6]*m[13] - m[12]*m[5]*m[10] + m[12]*m[6]*m[9];
    inv[1]  = -m[1]*m[10]*m[15] + m[1]*m[11]*m[14] + m[9]*m[2]*m[15] - m[9]*m[3]*m[14] - m[13]*m[2]*m[11] + m[13]*m[3]*m[10];
    inv[5]  =  m[0]*m[10]*m[15] - m[0]*m[11]*m[14] - m[8]*m[2]*m[15] + m[8]*m[3]*m[14] + m[12]*m[2]*m[11] - m[12]*m[3]*m[10];
    inv[9]  = -m[0]*m[9]*m[15]  + m[0]*m[11]*m[13] + m[8]*m[1]*m[15] - m[8]*m[3]*m[13] - m[12]*m[1]*m[11] + m[12]*m[3]*m[9];
    inv[13] =  m[0]*m[9]*m[14]  - m[0]*m[10]*m[13] - m[8]*m[1]*m[14] + m[8]*m[2]*m[13] + m[12]*m[1]*m[10] - m[12]*m[2]*m[9];
    inv[2]  =  m[1]*m[6]*m[15]  - m[1]*m[7]*m[14]  - m[5]*m[2]*m[15] + m[5]*m[3]*m[14] + m[13]*m[2]*m[7]  - m[13]*m[3]*m[6];
    inv[6]  = -m[0]*m[6]*m[15]  + m[0]*m[7]*m[14]  + m[4]*m[2]*m[15] - m[4]*m[3]*m[14] - m[12]*m[2]*m[7]  + m[12]*m[3]*m[6];
    inv[10] =  m[0]*m[5]*m[15]  - m[0]*m[7]*m[13]  - m[4]*m[1]*m[15] + m[4]*m[3]*m[13] + m[12]*m[1]*m[7]  - m[12]*m[3]*m[5];
    inv[14] = -m[0]*m[5]*m[14]  + m[0]*m[6]*m[13]  + m[4]*m[1]*m[14] - m[4]*m[2]*m[13] - m[12]*m[1]*m[6]  + m[12]*m[2]*m[5];
    inv[3]  = -m[1]*m[6]*m[11]  + m[1]*m[7]*m[10]  + m[5]*m[2]*m[11] - m[5]*m[3]*m[10] - m[9]*m[2]*m[7]   + m[9]*m[3]*m[6];
    inv[7]  =  m[0]*m[6]*m[11]  - m[0]*m[7]*m[10]  - m[4]*m[2]*m[11] + m[4]*m[3]*m[10] + m[8]*m[2]*m[7]   - m[8]*m[3]*m[6];
    inv[11] = -m[0]*m[5]*m[11]  + m[0]*m[7]*m[9]   + m[4]*m[1]*m[11] - m[4]*m[3]*m[9]  - m[8]*m[1]*m[7]   + m[8]*m[3]*m[5];
    inv[15] =  m[0]*m[5]*m[10]  - m[0]*m[6]*m[9]   - m[4]*m[1]*m[10] + m[4]*m[2]*m[9]  + m[8]*m[1]*m[6]   - m[8]*m[2]*m[5];

    float det = m[0]*inv[0] + m[1]*inv[4] + m[2]*inv[8] + m[3]*inv[12];
    float rdet = 1.0f / det;
#pragma unroll
    for (int i = 0; i < 16; ++i) inv[i] *= rdet;

#pragma unroll
    for (int r = 0; r < 3; ++r)
#pragma unroll
        for (int c = 0; c < 4; ++c) {
            float acc = 0.f;
#pragma unroll
            for (int k = 0; k < 4; ++k) acc += inv[r*4 + k] * poseA[k*4 + c];
            T[r*4 + c] = acc;
        }
}

// ---------- per-pixel precompute: 4B entry {u:15b, v:15b, valid:1b} ----------
// fixed point: stored = rint((val+4096)*4), decode val = i*0.25 - 4096.
// 1.2 MB table -> L2-resident (4 MB/XCD).
__global__ __launch_bounds__(256) void table_kernel(
    const float* __restrict__ depthA, const float* __restrict__ depthB,
    const float* __restrict__ poseA,  const float* __restrict__ poseB,
    unsigned int* __restrict__ tbl) {
    const int pix = blockIdx.x * blockDim.x + threadIdx.x;
    if (pix >= NPIX) return;

    float T[12];
    make_T(poseA, poseB, T);

    const int u = pix % IMG_W;
    const int v = pix / IMG_W;
    const float z  = depthA[pix];
    const float dB = depthB[pix];
    const float x = ((float)u - CXc) * z / FXc;
    const float y = ((float)v - CYc) * z / FYc;
    const float pbx = T[0]*x + T[1]*y + T[2]*z  + T[3];
    const float pby = T[4]*x + T[5]*y + T[6]*z  + T[7];
    const float pbz = T[8]*x + T[9]*y + T[10]*z + T[11];
    const float uB = FXc * pbx / pbz + CXc;
    const float vB = FYc * pby / pbz + CYc;
    const float uBi = truncf(uB);
    const float vBi = truncf(vB);
    const bool valid = (z > 0.f)
        & (uBi > 0.f) & (uBi < (float)IMG_W)
        & (vBi > 0.f) & (vBi < (float)IMG_H)
        & (dB > 0.f) & (dB >= pbz - DEPTH_MARGIN);
    const float uq = fminf(fmaxf(uB, -4095.f), 4095.f);
    const float vq = fminf(fmaxf(vB, -4095.f), 4095.f);
    const unsigned int iu = (unsigned int)(int)__builtin_rintf((uq + 4096.f) * 4.f); // [4,32764]
    const unsigned int iv = (unsigned int)(int)__builtin_rintf((vq + 4096.f) * 4.f);
    tbl[pix] = iu | (iv << 15) | ((valid ? 1u : 0u) << 30);
}

// ---------- main kernel: strided sample->thread map, L1-bypass gathers ----------
// thread t handles samples {base + m*256 + t}:
//   idx loads  : 64 lanes x 4B contiguous (256 B), non-temporal
//   gathers    : 1 per sample, 4B, sc0 (agent-scope) -> bypass L1, serve from L2,
//                no 64B L1 line fill per divergent lane (the TCP-fill wall)
//   out stores : 64 lanes x 12B contiguous (768 B, dwordx3)
// No LDS, no barrier -> 8 blocks/CU.
__global__ __launch_bounds__(256, 8) void sample_kernel(
    const int* __restrict__ uA, const int* __restrict__ vA,
    const unsigned int* __restrict__ tbl, float* __restrict__ out, int n) {
    const int t = threadIdx.x;
    const long long base = (long long)blockIdx.x * SPB;

    if (base + SPB <= (long long)n) {
        const int b = (int)base;
        int uu[SPT], vv[SPT];
#pragma unroll
        for (int m = 0; m < SPT; ++m) {
            const int s = b + m * TPB + t;
            uu[m] = __builtin_nontemporal_load(&uA[s]);
            vv[m] = __builtin_nontemporal_load(&vA[s]);
        }
        // all 8 gathers in flight before any use; sc0 -> no L1 allocate/fill
        unsigned int g[SPT];
#pragma unroll
        for (int m = 0; m < SPT; ++m) {
            const unsigned int* p = &tbl[vv[m] * IMG_W + uu[m]];
            g[m] = __hip_atomic_load(p, __ATOMIC_RELAXED, __HIP_MEMORY_SCOPE_AGENT);
        }

#pragma unroll
        for (int m = 0; m < SPT; ++m) {
            const int s = b + m * TPB + t;
            const float fu = (float)(g[m] & 0x7FFFu)         * 0.25f - 4096.f;
            const float fv = (float)((g[m] >> 15) & 0x7FFFu) * 0.25f - 4096.f;
            const float fl = (float)((g[m] >> 30) & 1u);
            float3 w; w.x = fu; w.y = fv; w.z = fl;
            *(float3*)(out + (size_t)s * 3) = w;   // lane-contiguous 12B -> 768B/wave
        }
    } else {
        // partial tail block
        for (long long s = base + t; s < (long long)n; s += TPB) {
            const unsigned int g = tbl[vA[s] * IMG_W + uA[s]];
            out[s*3 + 0] = (float)(g & 0x7FFFu)         * 0.25f - 4096.f;
            out[s*3 + 1] = (float)((g >> 15) & 0x7FFFu) * 0.25f - 4096.f;
            out[s*3 + 2] = (float)((g >> 30) & 1u);
        }
    }
}

extern "C" void kernel_launch(void* const* d_in, const int* in_sizes, int n_in,
                              void* d_out, int out_size, void* d_ws, size_t ws_size,
                              hipStream_t stream) {
    // inputs: 0 in_A(unused) 1 depth_A 2 pose_A 3 in_B(unused) 4 depth_B 5 pose_B 6 u_A 7 v_A
    const float* depthA = (const float*)d_in[1];
    const float* poseA  = (const float*)d_in[2];
    const float* depthB = (const float*)d_in[4];
    const float* poseB  = (const float*)d_in[5];
    const int*   uA     = (const int*)d_in[6];
    const int*   vA     = (const int*)d_in[7];
    float* out = (float*)d_out;

    unsigned int* tbl = (unsigned int*)d_ws;       // 1.2 MB

    const int n = in_sizes[6];

    table_kernel<<<(NPIX + 255) / 256, 256, 0, stream>>>(depthA, depthB, poseA, poseB, tbl);

    const int blocks = (int)(((long long)n + SPB - 1) / SPB);
    sample_kernel<<<blocks, TPB, 0, stream>>>(uA, vA, tbl, out, n);
}

// Round 8
// 55.494 us; speedup vs baseline: 1.3784x; 1.3784x over previous
//
#include <hip/hip_runtime.h>

#define FXc 384.996f
#define FYc 384.996f
#define CXc 325.85f
#define CYc 237.646f
#define DEPTH_MARGIN 0.003f
#define IMG_H 480
#define IMG_W 640
#define NPIX (IMG_H * IMG_W)

#define SPT 16                // samples per thread (2 pipelined halves of 8)
#define TPB 256               // threads per block
#define SPB (SPT * TPB)       // samples per block = 4096

// ---------- device helper: T = inv(pose_B) @ pose_A (rows 0..2) ----------
__device__ __forceinline__ void make_T(const float* __restrict__ poseA,
                                       const float* __restrict__ poseB,
                                       float* __restrict__ T /*12*/) {
    float m[16], inv[16];
#pragma unroll
    for (int i = 0; i < 16; ++i) m[i] = poseB[i];

    inv[0]  =  m[5]*m[10]*m[15] - m[5]*m[11]*m[14] - m[9]*m[6]*m[15] + m[9]*m[7]*m[14] + m[13]*m[6]*m[11] - m[13]*m[7]*m[10];
    inv[4]  = -m[4]*m[10]*m[15] + m[4]*m[11]*m[14] + m[8]*m[6]*m[15] - m[8]*m[7]*m[14] - m[12]*m[6]*m[11] + m[12]*m[7]*m[10];
    inv[8]  =  m[4]*m[9]*m[15]  - m[4]*m[11]*m[13] - m[8]*m[5]*m[15] + m[8]*m[7]*m[13] + m[12]*m[5]*m[11] - m[12]*m[7]*m[9];
    inv[12] = -m[4]*m[9]*m[14]  + m[4]*m[10]*m[13] + m[8]*m[5]*m[14] - m[8]*m[6]*m[13] - m[12]*m[5]*m[10] + m[12]*m[6]*m[9];
    inv[1]  = -m[1]*m[10]*m[15] + m[1]*m[11]*m[14] + m[9]*m[2]*m[15] - m[9]*m[3]*m[14] - m[13]*m[2]*m[11] + m[13]*m[3]*m[10];
    inv[5]  =  m[0]*m[10]*m[15] - m[0]*m[11]*m[14] - m[8]*m[2]*m[15] + m[8]*m[3]*m[14] + m[12]*m[2]*m[11] - m[12]*m[3]*m[10];
    inv[9]  = -m[0]*m[9]*m[15]  + m[0]*m[11]*m[13] + m[8]*m[1]*m[15] - m[8]*m[3]*m[13] - m[12]*m[1]*m[11] + m[12]*m[3]*m[9];
    inv[13] =  m[0]*m[9]*m[14]  - m[0]*m[10]*m[13] - m[8]*m[1]*m[14] + m[8]*m[2]*m[13] + m[12]*m[1]*m[10] - m[12]*m[2]*m[9];
    inv[2]  =  m[1]*m[6]*m[15]  - m[1]*m[7]*m[14]  - m[5]*m[2]*m[15] + m[5]*m[3]*m[14] + m[13]*m[2]*m[7]  - m[13]*m[3]*m[6];
    inv[6]  = -m[0]*m[6]*m[15]  + m[0]*m[7]*m[14]  + m[4]*m[2]*m[15] - m[4]*m[3]*m[14] - m[12]*m[2]*m[7]  + m[12]*m[3]*m[6];
    inv[10] =  m[0]*m[5]*m[15]  - m[0]*m[7]*m[13]  - m[4]*m[1]*m[15] + m[4]*m[3]*m[13] + m[12]*m[1]*m[7]  - m[12]*m[3]*m[5];
    inv[14] = -m[0]*m[5]*m[14]  + m[0]*m[6]*m[13]  + m[4]*m[1]*m[14] - m[4]*m[2]*m[13] - m[12]*m[1]*m[6]  + m[12]*m[2]*m[5];
    inv[3]  = -m[1]*m[6]*m[11]  + m[1]*m[7]*m[10]  + m[5]*m[2]*m[11] - m[5]*m[3]*m[10] - m[9]*m[2]*m[7]   + m[9]*m[3]*m[6];
    inv[7]  =  m[0]*m[6]*m[11]  - m[0]*m[7]*m[10]  - m[4]*m[2]*m[11] + m[4]*m[3]*m[10] + m[8]*m[2]*m[7]   - m[8]*m[3]*m[6];
    inv[11] = -m[0]*m[5]*m[11]  + m[0]*m[7]*m[9]   + m[4]*m[1]*m[11] - m[4]*m[3]*m[9]  - m[8]*m[1]*m[7]   + m[8]*m[3]*m[5];
    inv[15] =  m[0]*m[5]*m[10]  - m[0]*m[6]*m[9]   - m[4]*m[1]*m[10] + m[4]*m[2]*m[9]  + m[8]*m[1]*m[6]   - m[8]*m[2]*m[5];

    float det = m[0]*inv[0] + m[1]*inv[4] + m[2]*inv[8] + m[3]*inv[12];
    float rdet = 1.0f / det;
#pragma unroll
    for (int i = 0; i < 16; ++i) inv[i] *= rdet;

#pragma unroll
    for (int r = 0; r < 3; ++r)
#pragma unroll
        for (int c = 0; c < 4; ++c) {
            float acc = 0.f;
#pragma unroll
            for (int k = 0; k < 4; ++k) acc += inv[r*4 + k] * poseA[k*4 + c];
            T[r*4 + c] = acc;
        }
}

// ---------- per-pixel precompute: 4B entry {u:15b, v:15b, valid:1b} ----------
// fixed point: stored = rint((val+4096)*4), decode val = i*0.25 - 4096.
// 1.2 MB table -> L2-resident (4 MB/XCD).
__global__ __launch_bounds__(256) void table_kernel(
    const float* __restrict__ depthA, const float* __restrict__ depthB,
    const float* __restrict__ poseA,  const float* __restrict__ poseB,
    unsigned int* __restrict__ tbl) {
    const int pix = blockIdx.x * blockDim.x + threadIdx.x;
    if (pix >= NPIX) return;

    float T[12];
    make_T(poseA, poseB, T);

    const int u = pix % IMG_W;
    const int v = pix / IMG_W;
    const float z  = depthA[pix];
    const float dB = depthB[pix];
    const float x = ((float)u - CXc) * z / FXc;
    const float y = ((float)v - CYc) * z / FYc;
    const float pbx = T[0]*x + T[1]*y + T[2]*z  + T[3];
    const float pby = T[4]*x + T[5]*y + T[6]*z  + T[7];
    const float pbz = T[8]*x + T[9]*y + T[10]*z + T[11];
    const float uB = FXc * pbx / pbz + CXc;
    const float vB = FYc * pby / pbz + CYc;
    const float uBi = truncf(uB);
    const float vBi = truncf(vB);
    const bool valid = (z > 0.f)
        & (uBi > 0.f) & (uBi < (float)IMG_W)
        & (vBi > 0.f) & (vBi < (float)IMG_H)
        & (dB > 0.f) & (dB >= pbz - DEPTH_MARGIN);
    const float uq = fminf(fmaxf(uB, -4095.f), 4095.f);
    const float vq = fminf(fmaxf(vB, -4095.f), 4095.f);
    const unsigned int iu = (unsigned int)(int)__builtin_rintf((uq + 4096.f) * 4.f); // [4,32764]
    const unsigned int iv = (unsigned int)(int)__builtin_rintf((vq + 4096.f) * 4.f);
    tbl[pix] = iu | (iv << 15) | ((valid ? 1u : 0u) << 30);
}

// ---------- main kernel: SPT=16, strided map, 2-stage pipelined gathers ----------
// thread t handles samples {base + m*256 + t, m=0..15}:
//   idx loads  : 64 lanes x 4B contiguous (256 B/instr), PLAIN (L3-cacheable)
//   gathers    : 1 per sample, 4B from L2-resident table; 8-16 in flight/thread
//   out stores : 64 lanes x 12B contiguous (768 B/wave, dwordx3)
// No LDS, no barrier. Grid = 2048 blocks = exactly 8 blocks/CU on 256 CUs.
__global__ __launch_bounds__(256, 8) void sample_kernel(
    const int* __restrict__ uA, const int* __restrict__ vA,
    const unsigned int* __restrict__ tbl, float* __restrict__ out, int n) {
    const int t = threadIdx.x;
    const long long base = (long long)blockIdx.x * SPB;

    if (base + SPB <= (long long)n) {
        const int b = (int)base;
        // ---- half 0: idx loads + gathers issued ----
        int u0[8], v0[8];
#pragma unroll
        for (int m = 0; m < 8; ++m) {
            const int s = b + m * TPB + t;
            u0[m] = uA[s];
            v0[m] = vA[s];
        }
        unsigned int g0[8];
#pragma unroll
        for (int m = 0; m < 8; ++m) g0[m] = tbl[v0[m] * IMG_W + u0[m]];

        // ---- half 1: idx loads + gathers issued (overlap half-0 latency) ----
        int u1[8], v1[8];
#pragma unroll
        for (int m = 0; m < 8; ++m) {
            const int s = b + (8 + m) * TPB + t;
            u1[m] = uA[s];
            v1[m] = vA[s];
        }
        unsigned int g1[8];
#pragma unroll
        for (int m = 0; m < 8; ++m) g1[m] = tbl[v1[m] * IMG_W + u1[m]];

        // ---- store half 0 (waits only on g0; g1 still in flight) ----
#pragma unroll
        for (int m = 0; m < 8; ++m) {
            const int s = b + m * TPB + t;
            const float fu = (float)(g0[m] & 0x7FFFu)         * 0.25f - 4096.f;
            const float fv = (float)((g0[m] >> 15) & 0x7FFFu) * 0.25f - 4096.f;
            const float fl = (float)((g0[m] >> 30) & 1u);
            float3 w; w.x = fu; w.y = fv; w.z = fl;
            *(float3*)(out + (size_t)s * 3) = w;
        }
        // ---- store half 1 ----
#pragma unroll
        for (int m = 0; m < 8; ++m) {
            const int s = b + (8 + m) * TPB + t;
            const float fu = (float)(g1[m] & 0x7FFFu)         * 0.25f - 4096.f;
            const float fv = (float)((g1[m] >> 15) & 0x7FFFu) * 0.25f - 4096.f;
            const float fl = (float)((g1[m] >> 30) & 1u);
            float3 w; w.x = fu; w.y = fv; w.z = fl;
            *(float3*)(out + (size_t)s * 3) = w;
        }
    } else {
        // partial tail block
        for (long long s = base + t; s < (long long)n; s += TPB) {
            const unsigned int g = tbl[vA[s] * IMG_W + uA[s]];
            out[s*3 + 0] = (float)(g & 0x7FFFu)         * 0.25f - 4096.f;
            out[s*3 + 1] = (float)((g >> 15) & 0x7FFFu) * 0.25f - 4096.f;
            out[s*3 + 2] = (float)((g >> 30) & 1u);
        }
    }
}

extern "C" void kernel_launch(void* const* d_in, const int* in_sizes, int n_in,
                              void* d_out, int out_size, void* d_ws, size_t ws_size,
                              hipStream_t stream) {
    // inputs: 0 in_A(unused) 1 depth_A 2 pose_A 3 in_B(unused) 4 depth_B 5 pose_B 6 u_A 7 v_A
    const float* depthA = (const float*)d_in[1];
    const float* poseA  = (const float*)d_in[2];
    const float* depthB = (const float*)d_in[4];
    const float* poseB  = (const float*)d_in[5];
    const int*   uA     = (const int*)d_in[6];
    const int*   vA     = (const int*)d_in[7];
    float* out = (float*)d_out;

    unsigned int* tbl = (unsigned int*)d_ws;       // 1.2 MB

    const int n = in_sizes[6];

    table_kernel<<<(NPIX + 255) / 256, 256, 0, stream>>>(depthA, depthB, poseA, poseB, tbl);

    const int blocks = (int)(((long long)n + SPB - 1) / SPB);
    sample_kernel<<<blocks, TPB, 0, stream>>>(uA, vA, tbl, out, n);
}